// Round 7
// baseline (114.121 us; speedup 1.0000x reference)
//
#include <hip/hip_runtime.h>

// CMDNet_58274116272706 — B=16384, NR=64, NT=32, M=4, NITER=64.
// Phase 1: HH = Ht^T Ht per batch via f16 MFMA (Gram trick: A-frag == B-frag),
//          yH = y^T Ht in f32 VALU. Two passes of 2 batches each -> VGPR=60,
//          no spills (R6 verified: WRITE_SIZE exactly 10240 KB).
// Phase 2: 64 gradient steps. 4 batches per wave, 2 per lane (ILP=2).
//          R7: all elementwise f32 math packed as float2 (A,B) -> VOP3P
//          v_pk_fma_f32 etc., halving VALU issue slots for f32 ops.
//          HH columns as f16 pairs in VGPRs, matvec via v_dot2_f32_f16,
//          xt broadcast through f16 LDS, taui/delta via v_readlane,
//          softmax exp2-domain WITH max-subtraction (R5: removing it NaNs).
// amdgpu_waves_per_eu(4,4): grid = 4 blocks/CU = 4 waves/SIMD max; cap the
// allocator so it never trades spills for unreachable occupancy (R4 lesson).

#define NRr 64
#define NTt 32
#define NITER 64
#define B_TOTAL 16384

using f16x8  = __attribute__((ext_vector_type(8))) _Float16;
using h16x2  = __attribute__((ext_vector_type(2))) _Float16;
using f32x2  = __attribute__((ext_vector_type(2))) float;
using f32x16 = __attribute__((ext_vector_type(16))) float;

static __device__ __forceinline__ uint32_t pk16(float a, float b) {
    union { _Float16 h[2]; uint32_t u; } x;
    x.h[0] = (_Float16)a; x.h[1] = (_Float16)b;   // RNE
    return x.u;
}

static __device__ __forceinline__ float fdot2u(uint32_t a, uint32_t b, float c) {
    union { uint32_t u; h16x2 h; } x, y;
    x.u = a; y.u = b;
#if __has_builtin(__builtin_amdgcn_fdot2)
    return __builtin_amdgcn_fdot2(x.h, y.h, c, false);
#else
    return c + (float)x.h[0] * (float)y.h[0] + (float)x.h[1] * (float)y.h[1];
#endif
}

static __device__ __forceinline__ float exp2fast(float x) {
#if __has_builtin(__builtin_amdgcn_exp2f)
    return __builtin_amdgcn_exp2f(x);
#else
    return exp2f(x);
#endif
}

static __device__ __forceinline__ f32x2 exp2v(f32x2 x) {
    f32x2 r; r[0] = exp2fast(x[0]); r[1] = exp2fast(x[1]); return r;
}

static __device__ __forceinline__ f32x2 fma2(f32x2 a, f32x2 b, f32x2 c) {
    return __builtin_elementwise_fma(a, b, c);
}
static __device__ __forceinline__ f32x2 max2(f32x2 a, f32x2 b) {
    return __builtin_elementwise_max(a, b);
}
static __device__ __forceinline__ f32x2 bc2(float s) {   // broadcast
    f32x2 r; r[0] = s; r[1] = s; return r;
}

static __device__ __forceinline__ float rdlane(float v, int lane) {
    return __builtin_bit_cast(float,
        __builtin_amdgcn_readlane(__builtin_bit_cast(int, v), lane));
}

static __device__ __forceinline__ float rfl(float v) {
    return __builtin_bit_cast(float,
        __builtin_amdgcn_readfirstlane(__builtin_bit_cast(int, v)));
}

// Gram fragment + y-partial for one batch. ap[8] = f16-packed row-pair
// stripes of column j (rows 8g+4hi+2cc, +1), ypart = y·H over this lane's ks.
static __device__ __forceinline__ void gram_one(
    const float* __restrict__ hp, const float* __restrict__ ypt,
    const int hi, uint32_t ap[8], float& ypart_out)
{
    f32x16 acc = {};
    float  ypart = 0.f;
#pragma unroll
    for (int kc = 0; kc < 4; ++kc) {
        const int kb = kc * 16 + hi * 8;      // this lane's 8 k values
        float h[8];
#pragma unroll
        for (int e = 0; e < 8; ++e) h[e] = hp[(size_t)(kb + e) * NTt];
        const float4 ya = *(const float4*)(ypt + kb);
        const float4 yb = *(const float4*)(ypt + kb + 4);
        ypart += h[0]*ya.x + h[1]*ya.y + h[2]*ya.z + h[3]*ya.w
               + h[4]*yb.x + h[5]*yb.y + h[6]*yb.z + h[7]*yb.w;
        f16x8 fa;
#pragma unroll
        for (int e = 0; e < 8; ++e) fa[e] = (_Float16)h[e];
        // A-frag == B-frag: Gram product is k-permutation-insensitive.
        acc = __builtin_amdgcn_mfma_f32_32x32x16_f16(fa, fa, acc, 0, 0, 0);
    }
    // C layout: col=lane&31, row=(r&3)+8*(r>>2)+4*hi. Pack row pairs.
#pragma unroll
    for (int g = 0; g < 4; ++g) {
        ap[2*g+0] = pk16(acc[4*g+0], acc[4*g+1]);
        ap[2*g+1] = pk16(acc[4*g+2], acc[4*g+3]);
    }
    ypart_out = ypart;
}

// Exchange stripes with lane^32 and assemble full 32-row column (16 pairs).
static __device__ __forceinline__ void exch_hh(
    const uint32_t apx[8], const uint32_t apy[8], const int hi, uint32_t hh[16])
{
#pragma unroll
    for (int p = 0; p < 8; ++p) {
        const uint32_t snd = hi ? apx[p] : apy[p];        // partner's batch
        const uint32_t rcv = (uint32_t)__shfl_xor((int)snd, 32, 64);
        const uint32_t own = hi ? apy[p] : apx[p];
        const int g = p >> 1, cc = p & 1;
        hh[4*g + cc]     = hi ? rcv : own;    // stripe 0 (rows 8g+2cc,+1)
        hh[4*g + 2 + cc] = hi ? own : rcv;    // stripe 1 (rows 8g+4+2cc,+1)
    }
}

__global__ __launch_bounds__(256)
__attribute__((amdgpu_waves_per_eu(4, 4)))
void cmdnet_kernel(
    const float* __restrict__ yt,     // [B,64]
    const float* __restrict__ Ht,     // [B,64,32]
    const float* __restrict__ sig0,   // [B]
    const float* __restrict__ mm,     // [4]
    const float* __restrict__ alpha,  // [4]
    const float* __restrict__ taui,   // [65]
    const float* __restrict__ delta,  // [64]
    float* __restrict__ out)          // ft [B,32,4] then xt [B,32]
{
    __shared__ __align__(16) _Float16 xtsh[4][4][32];  // [wave][batch-slot][nt]

    const int tid = threadIdx.x;
    const int w   = tid >> 6;                 // wave in block
    const int l   = tid & 63;                 // lane
    const int j   = l & 31;                   // nt / matrix column
    const int hi  = l >> 5;                   // half-wave id
    const int c0  = (blockIdx.x * 4 + w) * 4; // wave's 4 batches

    // Per-iteration scalars parked in lane-indexed VGPRs (readlane in loop)
    const float vta = fabsf(taui[l]);         // |taui[it]| for it = lane
    const float vd  = delta[l];               // delta[it]

    const size_t hstride = (size_t)NRr * NTt;

    // ---------------- Phase 1: two passes of 2 batches each ----------------
    uint32_t hhA[16], hhB[16];
    float yHA_v, yHB_v;
    {   // pass 0: batches c0, c0+2 -> hhA (this lane keeps bA = c0+2*hi)
        uint32_t apx[8], apy[8];
        float ypx, ypy;
        gram_one(Ht + (size_t)(c0    ) * hstride + j, yt + (size_t)(c0    ) * NRr, hi, apx, ypx);
        gram_one(Ht + (size_t)(c0 + 2) * hstride + j, yt + (size_t)(c0 + 2) * NRr, hi, apy, ypy);
        exch_hh(apx, apy, hi, hhA);
        const float snd = hi ? ypx : ypy;
        const float rcv = __shfl_xor(snd, 32, 64);
        yHA_v = (hi ? ypy : ypx) + rcv;
    }
    {   // pass 1: batches c0+1, c0+3 -> hhB (this lane keeps bB = c0+2*hi+1)
        uint32_t apx[8], apy[8];
        float ypx, ypy;
        gram_one(Ht + (size_t)(c0 + 1) * hstride + j, yt + (size_t)(c0 + 1) * NRr, hi, apx, ypx);
        gram_one(Ht + (size_t)(c0 + 3) * hstride + j, yt + (size_t)(c0 + 3) * NRr, hi, apy, ypy);
        exch_hh(apx, apy, hi, hhB);
        const float snd = hi ? ypx : ypy;
        const float rcv = __shfl_xor(snd, 32, 64);
        yHB_v = (hi ? ypy : ypx) + rcv;
    }

    const int bA = c0 + 2*hi;
    const int bB = bA + 1;
    const float sgA = sig0[bA], sgB = sig0[bB];

    // Packed per-batch constants: [0]=A, [1]=B
    f32x2 sig2_2; sig2_2[0] = sgA * sgA; sig2_2[1] = sgB * sgB;
    f32x2 yH2;    yH2[0] = yHA_v;        yH2[1] = yHB_v;

    const float4 mv = *(const float4*)mm;
    const float4 av = *(const float4*)alpha;
    const float m0 = rfl(mv.x), m1 = rfl(mv.y), m2 = rfl(mv.z), m3 = rfl(mv.w);
    // exp2-domain softmax scores: (log2 a + G*log2e)*scale
    const float la0 = rfl(__log2f(av.x)), la1 = rfl(__log2f(av.y));
    const float la2 = rfl(__log2f(av.z)), la3 = rfl(__log2f(av.w));

    const float L2E  = 1.4426950408889634f;
    const float NL2E = -1.4426950408889634f;
    const f32x2 nl2e2 = bc2(NL2E);
    const f32x2 m02 = bc2(m0), m12 = bc2(m1), m22 = bc2(m2), m32 = bc2(m3);

    _Float16* xwA = &xtsh[w][2*hi][j];        // own batch slots
    _Float16* xwB = &xtsh[w][2*hi+1][j];
    const uint4* xr = (const uint4*)&xtsh[w][2*hi][0];  // [0..3]=A, [4..7]=B

    f32x2 G0 = bc2(0.f), G1 = bc2(0.f), G2 = bc2(0.f), G3 = bc2(0.f);

    // ---------------- Phase 2: 64 descent steps (packed f32) ---------------
    for (int it = 0; it < NITER; ++it) {
        const float ta  = rdlane(vta, it);
        const float d   = rdlane(vd,  it);
        const float sc  = (it == 0) ? 1.0f : ta;  // first layer: scale 1
        const float scL = sc * L2E;
        const float tad = ta * d;
        const f32x2 scL2 = bc2(scL);
        const f32x2 c1   = bc2(d) * sig2_2;       // pk_mul
        const f32x2 ls0v = bc2(la0 * sc), ls1v = bc2(la1 * sc);
        const f32x2 ls2v = bc2(la2 * sc), ls3v = bc2(la3 * sc);

        // softmax over M=4, exp2 domain, WITH max-subtraction — all packed
        const f32x2 s0 = fma2(G0, scL2, ls0v);
        const f32x2 s1 = fma2(G1, scL2, ls1v);
        const f32x2 s2 = fma2(G2, scL2, ls2v);
        const f32x2 s3 = fma2(G3, scL2, ls3v);
        const f32x2 mx = max2(max2(s0, s1), max2(s2, s3));
        const f32x2 e0 = exp2v(s0 - mx), e1 = exp2v(s1 - mx);
        const f32x2 e2 = exp2v(s2 - mx), e3 = exp2v(s3 - mx);
        const f32x2 Z  = (e0 + e1) + (e2 + e3);
        f32x2 R; R[0] = __builtin_amdgcn_rcpf(Z[0]);
                 R[1] = __builtin_amdgcn_rcpf(Z[1]);
        const f32x2 S  = fma2(e0, m02, fma2(e1, m12, fma2(e2, m22, e3 * m32)));
        const f32x2 xt = S * R;

        // broadcast xt within half-wave (same-wave DS ops are in-order)
        *xwA = (_Float16)xt[0];
        *xwB = (_Float16)xt[1];
        asm volatile("" ::: "memory");

        // barrier exps are independent of the LDS round-trip — overlap it
        const f32x2 en0 = exp2v(G0 * nl2e2), en1 = exp2v(G1 * nl2e2);
        const f32x2 en2 = exp2v(G2 * nl2e2), en3 = exp2v(G3 * nl2e2);

        const uint4 a0 = xr[0], a1 = xr[1], a2 = xr[2], a3 = xr[3];
        const uint4 b0 = xr[4], b1 = xr[5], b2 = xr[6], b3 = xr[7];
        asm volatile("" ::: "memory");

        // xHH via v_dot2_f32_f16 — 4 independent chains (already-packed f16)
        float pA0 = 0.f, pA1 = 0.f, pB0 = 0.f, pB1 = 0.f;
        pA0 = fdot2u(hhA[ 0], a0.x, pA0); pA1 = fdot2u(hhA[ 1], a0.y, pA1);
        pB0 = fdot2u(hhB[ 0], b0.x, pB0); pB1 = fdot2u(hhB[ 1], b0.y, pB1);
        pA0 = fdot2u(hhA[ 2], a0.z, pA0); pA1 = fdot2u(hhA[ 3], a0.w, pA1);
        pB0 = fdot2u(hhB[ 2], b0.z, pB0); pB1 = fdot2u(hhB[ 3], b0.w, pB1);
        pA0 = fdot2u(hhA[ 4], a1.x, pA0); pA1 = fdot2u(hhA[ 5], a1.y, pA1);
        pB0 = fdot2u(hhB[ 4], b1.x, pB0); pB1 = fdot2u(hhB[ 5], b1.y, pB1);
        pA0 = fdot2u(hhA[ 6], a1.z, pA0); pA1 = fdot2u(hhA[ 7], a1.w, pA1);
        pB0 = fdot2u(hhB[ 6], b1.z, pB0); pB1 = fdot2u(hhB[ 7], b1.w, pB1);
        pA0 = fdot2u(hhA[ 8], a2.x, pA0); pA1 = fdot2u(hhA[ 9], a2.y, pA1);
        pB0 = fdot2u(hhB[ 8], b2.x, pB0); pB1 = fdot2u(hhB[ 9], b2.y, pB1);
        pA0 = fdot2u(hhA[10], a2.z, pA0); pA1 = fdot2u(hhA[11], a2.w, pA1);
        pB0 = fdot2u(hhB[10], b2.z, pB0); pB1 = fdot2u(hhB[11], b2.w, pB1);
        pA0 = fdot2u(hhA[12], a3.x, pA0); pA1 = fdot2u(hhA[13], a3.y, pA1);
        pB0 = fdot2u(hhB[12], b3.x, pB0); pB1 = fdot2u(hhB[13], b3.y, pB1);
        pA0 = fdot2u(hhA[14], a3.z, pA0); pA1 = fdot2u(hhA[15], a3.w, pA1);
        pB0 = fdot2u(hhB[14], b3.z, pB0); pB1 = fdot2u(hhB[15], b3.w, pB1);

        f32x2 p; p[0] = pA0 + pA1; p[1] = pB0 + pB1;
        const f32x2 qd = p - yH2;                 // pk_sub
        const f32x2 tq = (bc2(tad) * qd) * R;     // folds ta, delta, 1/Z

        // G' = (G - c1) + c1*exp(-G) - tq * e_i * (m_i - xt)  — packed
        G0 = fma2(-tq, e0 * (m02 - xt), fma2(c1, en0, G0 - c1));
        G1 = fma2(-tq, e1 * (m12 - xt), fma2(c1, en1, G1 - c1));
        G2 = fma2(-tq, e2 * (m22 - xt), fma2(c1, en2, G2 - c1));
        G3 = fma2(-tq, e3 * (m32 - xt), fma2(c1, en3, G3 - c1));
    }

    // ---------------- Final layer: softmax + soft symbol, store ------------
    // scores: (ln a + G)*ta == (log2 a + G*log2e)*ta in exp2 domain
    const float tap = fabsf(taui[NITER]);
    {
        const f32x2 tap2 = bc2(tap);
        const f32x2 l2e2 = bc2(L2E);
        const f32x2 w0 = fma2(G0, l2e2, bc2(la0)) * tap2;
        const f32x2 w1 = fma2(G1, l2e2, bc2(la1)) * tap2;
        const f32x2 w2 = fma2(G2, l2e2, bc2(la2)) * tap2;
        const f32x2 w3 = fma2(G3, l2e2, bc2(la3)) * tap2;
        const f32x2 mx = max2(max2(w0, w1), max2(w2, w3));
        const f32x2 e0 = exp2v(w0 - mx), e1 = exp2v(w1 - mx);
        const f32x2 e2 = exp2v(w2 - mx), e3 = exp2v(w3 - mx);
        const f32x2 Z  = (e0 + e1) + (e2 + e3);
        f32x2 R; R[0] = __builtin_amdgcn_rcpf(Z[0]);
                 R[1] = __builtin_amdgcn_rcpf(Z[1]);
        const f32x2 f0 = e0 * R, f1 = e1 * R, f2 = e2 * R, f3 = e3 * R;
        const f32x2 xt = fma2(f0, m02, fma2(f1, m12, fma2(f2, m22, f3 * m32)));

#pragma unroll
        for (int s = 0; s < 2; ++s) {
            const int bm = s ? bB : bA;
            float4 f4; f4.x = f0[s]; f4.y = f1[s]; f4.z = f2[s]; f4.w = f3[s];
            *(float4*)(out + ((size_t)bm * NTt + j) * 4) = f4;
            out[(size_t)B_TOTAL * NTt * 4 + (size_t)bm * NTt + j] = xt[s];
        }
    }
}

extern "C" void kernel_launch(void* const* d_in, const int* in_sizes, int n_in,
                              void* d_out, int out_size, void* d_ws, size_t ws_size,
                              hipStream_t stream) {
    const float* yt    = (const float*)d_in[0];
    const float* Ht    = (const float*)d_in[1];
    const float* sig0  = (const float*)d_in[2];
    const float* mm    = (const float*)d_in[3];
    const float* alpha = (const float*)d_in[4];
    const float* taui  = (const float*)d_in[5];
    const float* delta = (const float*)d_in[6];
    float* out = (float*)d_out;

    const int blocks = B_TOTAL / 16;  // 16 batches per 256-thread block
    cmdnet_kernel<<<blocks, 256, 0, stream>>>(yt, Ht, sig0, mm, alpha, taui,
                                              delta, out);
}